// Round 9
// baseline (528.784 us; speedup 1.0000x reference)
//
#include <hip/hip_runtime.h>
#include <hip/hip_bf16.h>

#define T 252
#define NOUT 500
#define NSEL 20
#define UBV 0.1f

// LDS activation planes: [row = 16 zero-pad + 256 t][64 ch bf16 = 128 B], XOR-swizzled
// 16B chunks: chunk' = chunk ^ (row & 7). Row stride 32 dwords, 272 rows, 2 planes.
#define ROWS 272
#define PLANE_U (ROWS * 32)           // 8704 uints per plane
#define LDS_BYTES (2 * PLANE_U * 4)   // 69632 B

// ws layout (floats):
//   [0)        AF : W MFMA A-frags, 384 frags x 256 dwords    98304
//   [98304)    awT : attn_w^T [c][a]                          32000
//   [130304)   fwT : fc_w^T   [c][a]                          32000
//   [162304)   pooled [B][64]                                 131072
#define OFF_AWT    98304
#define OFF_FWT    130304
#define OFF_POOLED 162304

typedef short bf8 __attribute__((ext_vector_type(8)));   // 8 bf16 = 4 VGPR
typedef float f32x4 __attribute__((ext_vector_type(4)));

static __device__ __forceinline__ unsigned short f2bf(float f) {
    unsigned u = __float_as_uint(f);
    return (unsigned short)((u + 0x7fffu + ((u >> 16) & 1u)) >> 16);   // RNE
}
static __device__ __forceinline__ float bf2f(unsigned short h) {
    return __uint_as_float(((unsigned)h) << 16);
}
// pack two floats -> two bf16 (RNE); lowers to v_cvt_pk_bf16_f32 where available
static __device__ __forceinline__ unsigned pk2bf(float a, float b) {
    __hip_bfloat162 h = __float22bfloat162_rn(float2{a, b});
    unsigned u; __builtin_memcpy(&u, &h, 4); return u;
}
static __device__ __forceinline__ float bf_lo_f(unsigned u) { return __uint_as_float(u << 16); }
static __device__ __forceinline__ float bf_hi_f(unsigned u) { return __uint_as_float(u & 0xffff0000u); }
// uint index of 16B chunk base, swizzled
static __device__ __forceinline__ int swz(int row, int chunk) {
    return row * 32 + ((chunk ^ (row & 7)) << 2);
}

// ---------- prep: pack W into A-fragments + head transposes ----------
// fragid = ((((buf*4+lvl)*2+Kt)*3+tap)*4+m)*2+s ; per frag: [lane][4 dwords]
// A-frag lane map (16x16x32 bf16): c = m*16 + (lane&15), i = Kt*32 + (lane>>4)*8 + j
__global__ __launch_bounds__(256) void prep_kernel(
    const float* __restrict__ w1, const float* __restrict__ w2,
    const float* __restrict__ aw, const float* __restrict__ fw,
    float* __restrict__ ws)
{
    int gid = blockIdx.x * 256 + threadIdx.x;
    if (gid < 24576) {
        int frag = gid >> 6, lane = gid & 63;
        int s   = frag & 1;
        int m   = (frag >> 1) & 3;
        int t3  = frag >> 3;
        int tap = t3 % 3;
        int q   = t3 / 3;
        int Kt  = q & 1;
        int lvl = (q >> 1) & 3;
        int buf = q >> 3;
        int c  = m * 16 + (lane & 15);
        int i0 = Kt * 32 + (lane >> 4) * 8;
        const float* W = (buf ? w2 : w1) + lvl * 12288 + c * 192;
        unsigned short v[8];
        for (int j = 0; j < 8; ++j) {
            float x = W[(i0 + j) * 3 + tap];
            unsigned short hi = f2bf(x);
            if (s == 0) v[j] = hi;
            else        v[j] = f2bf(x - bf2f(hi));
        }
        unsigned* dst = (unsigned*)ws + frag * 256 + lane * 4;
        for (int d = 0; d < 4; ++d)
            dst[d] = (unsigned)v[2 * d] | ((unsigned)v[2 * d + 1] << 16);
    }
    if (gid < 32000) {
        int a = gid >> 6, c = gid & 63;   // src [a][c]
        ws[OFF_AWT + c * 500 + a] = aw[gid];
        ws[OFF_FWT + c * 500 + a] = fw[gid];
    }
}

extern __shared__ unsigned short lds[];

#define MFMA(A, B, C) __builtin_amdgcn_mfma_f32_16x16x32_bf16((A), (B), (C), 0, 0, 0)

// one 64ch x 64t conv GEMM for this wave: acc = bias + sum over (Kt,tap) of W*act.
// B fragments are software-pipelined 2-deep: phase p+1's ds_reads issue before
// phase p's MFMA burst, so the ~120cyc LDS latency hides under the burst.
static __device__ __forceinline__ void conv_mm(
    const uint4* __restrict__ AF4,
    const unsigned* __restrict__ Lh, const unsigned* __restrict__ Ll,
    const float* __restrict__ bias,
    int cvlvl, int d, int Rb, int g, int g4, int lane,
    f32x4 acc[4][4])
{
    #pragma unroll
    for (int m = 0; m < 4; ++m) {
        float4 bv = *(const float4*)(bias + m * 16 + g4);
        #pragma unroll
        for (int nn = 0; nn < 4; ++nn)
            acc[m][nn] = (f32x4){bv.x, bv.y, bv.z, bv.w};
    }

    bf8 Bh0[4], Bl0[4], Bh1[4], Bl1[4];
    // prologue: load phase 0 (Kt=0, tap=0) into buffer 0
    {
        const int row0 = Rb - 2 * d;
        const int ui0  = row0 * 32 + ((g ^ (row0 & 7)) << 2);
        #pragma unroll
        for (int nn = 0; nn < 4; ++nn) {
            Bh0[nn] = *(const bf8*)(Lh + ui0 + nn * 512);
            Bl0[nn] = *(const bf8*)(Ll + ui0 + nn * 512);
        }
    }

    #pragma unroll
    for (int p = 0; p < 6; ++p) {
        const int Kt  = p / 3;
        const int tap = p % 3;
        const int fb = ((cvlvl * 2 + Kt) * 3 + tap) * 8;
        const uint4* af = AF4 + fb * 64 + lane;
        uint4 ta[4], tb[4];
        #pragma unroll
        for (int m = 0; m < 4; ++m) { ta[m] = af[m * 128]; tb[m] = af[m * 128 + 64]; }

        // prefetch next phase's B into the alternate buffer (consumed next iter)
        if (p < 5) {
            const int Ktn  = (p + 1) / 3;
            const int tapn = (p + 1) % 3;
            const int shiftn = (2 - tapn) * d;
            const int rown   = Rb - shiftn;
            const int uin    = rown * 32 + ((((Ktn << 2) + g) ^ (rown & 7)) << 2);
            if ((p & 1) == 0) {
                #pragma unroll
                for (int nn = 0; nn < 4; ++nn) {
                    Bh1[nn] = *(const bf8*)(Lh + uin + nn * 512);
                    Bl1[nn] = *(const bf8*)(Ll + uin + nn * 512);
                }
            } else {
                #pragma unroll
                for (int nn = 0; nn < 4; ++nn) {
                    Bh0[nn] = *(const bf8*)(Lh + uin + nn * 512);
                    Bl0[nn] = *(const bf8*)(Ll + uin + nn * 512);
                }
            }
        }

        // T5: boost this wave while it drains the MFMA burst (R8: conv −21 µs)
        __builtin_amdgcn_s_setprio(1);
        #pragma unroll
        for (int m = 0; m < 4; ++m) {
            bf8 Ah = *(bf8*)&ta[m];
            bf8 Al = *(bf8*)&tb[m];
            #pragma unroll
            for (int nn = 0; nn < 4; ++nn) {
                f32x4 a = acc[m][nn];
                if ((p & 1) == 0) {
                    a = MFMA(Ah, Bh0[nn], a);
                    a = MFMA(Ah, Bl0[nn], a);   // hi*lo
                    a = MFMA(Al, Bh0[nn], a);   // lo*hi (lo*lo dropped: ~2^-18)
                } else {
                    a = MFMA(Ah, Bh1[nn], a);
                    a = MFMA(Ah, Bl1[nn], a);
                    a = MFMA(Al, Bh1[nn], a);
                }
                acc[m][nn] = a;
            }
        }
        __builtin_amdgcn_s_setprio(0);
    }
}

__global__ __launch_bounds__(256, 2) void conv_kernel(
    const float* __restrict__ x,
    const float* __restrict__ ws,
    const float* __restrict__ b1,
    const float* __restrict__ b2,
    float* __restrict__ pooled)
{
    const int b    = blockIdx.x;
    const int tid  = threadIdx.x;        // 0..255
    const int lane = tid & 63;
    const int wv   = tid >> 6;           // 4 waves; wave handles ntiles 4wv..4wv+3

    unsigned* Lh = (unsigned*)lds;
    unsigned* Ll = Lh + PLANE_U;

    // zero pad rows 0..15 (t<0) and 268..271 (t>=252), both planes (whole rows)
    for (int j = tid; j < 640; j += 256) {
        int r20 = j >> 5, col = j & 31;
        int r = (r20 < 16) ? r20 : (252 + r20);
        Lh[r * 32 + col] = 0u;
        Ll[r * 32 + col] = 0u;
    }
    // ingest x[b]: [252][64] fp32 -> split hi/lo bf16 planes (swizzled)
    const float4* xb = (const float4*)(x + (size_t)b * (T * 64));
    for (int v = tid; v < T * 16; v += 256) {
        float4 xv = xb[v];
        int t = v >> 4, f4 = v & 15;              // channel base = 4*f4
        unsigned h01 = pk2bf(xv.x, xv.y);
        unsigned h23 = pk2bf(xv.z, xv.w);
        unsigned l01 = pk2bf(xv.x - bf_lo_f(h01), xv.y - bf_hi_f(h01));
        unsigned l23 = pk2bf(xv.z - bf_lo_f(h23), xv.w - bf_hi_f(h23));
        int row = 16 + t;
        int ui = swz(row, f4 >> 1) + ((f4 & 1) << 1);
        Lh[ui]     = h01;
        Lh[ui + 1] = h23;
        Ll[ui]     = l01;
        Ll[ui + 1] = l23;
    }

    const int g    = lane >> 4;               // 0..3
    const int g4   = g << 2;
    const int ln16 = lane & 15;
    const int Rb   = 16 + 64 * wv + ln16;     // D/B row base for this thread (nn=0)

    // residual h in fp32 registers, D-layout: hr[m][nn][j] = h[c = m*16+g4+j][t = 64wv+16nn+ln16]
    float hr[4][4][4];
    #pragma unroll
    for (int m = 0; m < 4; ++m)
        #pragma unroll
        for (int nn = 0; nn < 4; ++nn) {
            int t = 64 * wv + 16 * nn + ln16;
            if (t < T) {
                float4 v = xb[t * 16 + m * 4 + g];
                hr[m][nn][0] = v.x; hr[m][nn][1] = v.y;
                hr[m][nn][2] = v.z; hr[m][nn][3] = v.w;
            } else {
                hr[m][nn][0] = 0.f; hr[m][nn][1] = 0.f;
                hr[m][nn][2] = 0.f; hr[m][nn][3] = 0.f;
            }
        }
    __syncthreads();

    const uint4* AF4 = (const uint4*)ws;

    // epilogue write bases (linear in nn: +512)
    int ue[4];
    #pragma unroll
    for (int m = 0; m < 4; ++m)
        ue[m] = Rb * 32 + (((2 * m + (g >> 1)) ^ (Rb & 7)) << 2) + ((g & 1) << 1);

    for (int lvl = 0; lvl < 4; ++lvl) {
        const int d = 1 << lvl;
        f32x4 acc[4][4];

        // ---- conv1: reads h-plane ----
        conv_mm(AF4, Lh, Ll, b1 + lvl * 64, 0 * 4 + lvl, d, Rb, g, g4, lane, acc);
        __syncthreads();   // all h-plane reads done
        #pragma unroll
        for (int m = 0; m < 4; ++m)
            #pragma unroll
            for (int nn = 0; nn < 4; ++nn) {
                float o0 = fmaxf(acc[m][nn][0], 0.f);
                float o1 = fmaxf(acc[m][nn][1], 0.f);
                float o2 = fmaxf(acc[m][nn][2], 0.f);
                float o3 = fmaxf(acc[m][nn][3], 0.f);
                uint2 wh, wl;
                wh.x = pk2bf(o0, o1);
                wh.y = pk2bf(o2, o3);
                wl.x = pk2bf(o0 - bf_lo_f(wh.x), o1 - bf_hi_f(wh.x));
                wl.y = pk2bf(o2 - bf_lo_f(wh.y), o3 - bf_hi_f(wh.y));
                int ui = ue[m] + nn * 512;
                *(uint2*)(Lh + ui) = wh;
                *(uint2*)(Ll + ui) = wl;
            }
        __syncthreads();   // o1 visible

        // ---- conv2: reads o1-plane ----
        conv_mm(AF4, Lh, Ll, b2 + lvl * 64, 1 * 4 + lvl, d, Rb, g, g4, lane, acc);
        // residual + relu, fp32 in registers
        #pragma unroll
        for (int m = 0; m < 4; ++m)
            #pragma unroll
            for (int nn = 0; nn < 4; ++nn)
                #pragma unroll
                for (int j = 0; j < 4; ++j)
                    hr[m][nn][j] = fmaxf(fmaxf(acc[m][nn][j], 0.f) + hr[m][nn][j], 0.f);

        if (lvl < 3) {
            __syncthreads();   // all o1-plane reads done
            #pragma unroll
            for (int m = 0; m < 4; ++m)
                #pragma unroll
                for (int nn = 0; nn < 4; ++nn) {
                    float h0 = hr[m][nn][0], h1 = hr[m][nn][1];
                    float h2 = hr[m][nn][2], h3 = hr[m][nn][3];
                    uint2 wh, wl;
                    wh.x = pk2bf(h0, h1);
                    wh.y = pk2bf(h2, h3);
                    wl.x = pk2bf(h0 - bf_lo_f(wh.x), h1 - bf_hi_f(wh.x));
                    wl.y = pk2bf(h2 - bf_lo_f(wh.y), h3 - bf_hi_f(wh.y));
                    int ui = ue[m] + nn * 512;
                    *(uint2*)(Lh + ui) = wh;
                    *(uint2*)(Ll + ui) = wl;
                }
            __syncthreads();   // h_new visible
        }
    }

    // ---- max-pool over t, directly from hr registers ----
    __syncthreads();           // lvl3 conv2 o1-plane reads done everywhere; LDS free
    {
        const bool t3ok = (64 * wv + 48 + ln16) < T;   // mask t>=252 garbage (wv==3 only)
        float pm[4][4];
        #pragma unroll
        for (int m = 0; m < 4; ++m)
            #pragma unroll
            for (int j = 0; j < 4; ++j) {
                float p = fmaxf(fmaxf(hr[m][0][j], hr[m][1][j]), hr[m][2][j]);
                if (t3ok) p = fmaxf(p, hr[m][3][j]);
                pm[m][j] = p;
            }
        #pragma unroll
        for (int off = 1; off < 16; off <<= 1)
            #pragma unroll
            for (int m = 0; m < 4; ++m)
                #pragma unroll
                for (int j = 0; j < 4; ++j)
                    pm[m][j] = fmaxf(pm[m][j], __shfl_xor(pm[m][j], off));
        float* fp = (float*)lds;
        if (ln16 == 0) {
            #pragma unroll
            for (int m = 0; m < 4; ++m)
                #pragma unroll
                for (int j = 0; j < 4; ++j)
                    fp[wv * 64 + m * 16 + g4 + j] = pm[m][j];
        }
        __syncthreads();
        if (tid < 64) {
            float mm = fmaxf(fmaxf(fp[tid], fp[tid + 64]),
                             fmaxf(fp[tid + 128], fp[tid + 192]));
            pooled[(size_t)b * 64 + tid] = mm;
        }
    }
}

// ---------- head: GEMVs + wave-local top-20 + softmax + wave-local rebalance ----------
__global__ __launch_bounds__(256) void head_kernel(
    const float* __restrict__ ws,
    const float* __restrict__ proj_w,
    const float* __restrict__ proj_b,
    const float* __restrict__ attn_b,
    const float* __restrict__ fc_b,
    float* __restrict__ out)
{
    const float* awT    = ws + OFF_AWT;
    const float* fwT    = ws + OFF_FWT;
    const float* pooled = ws + OFF_POOLED;

    __shared__ float z[64];
    __shared__ float att[512];
    __shared__ float pa[512];
    __shared__ int   msk[512];
    __shared__ float rs[4];

    const int b   = blockIdx.x;
    const int tid = threadIdx.x;
    const int wv  = tid >> 6, ln = tid & 63;

    // z = relu(pooled @ proj_w^T + proj_b) — 4 threads per output, shfl-reduced
    {
        const int outc = tid >> 2, part = tid & 3;
        const float* pw = proj_w + outc * 64 + part * 16;
        const float* pl = pooled + (size_t)b * 64 + part * 16;
        float s = 0.f;
        #pragma unroll
        for (int c = 0; c < 16; ++c) s = fmaf(pw[c], pl[c], s);
        s += __shfl_xor(s, 1);
        s += __shfl_xor(s, 2);
        if (part == 0) z[outc] = fmaxf(s + proj_b[outc], 0.f);
    }
    __syncthreads();

    const int a0  = tid;
    const int a1  = tid + 256;
    const int a1e = (a1 < NOUT) ? a1 : (NOUT - 1);

    // attn = sigmoid(z @ attn_w^T + attn_b); fc logits too (independent of top-k)
    float l0 = attn_b[a0], l1 = attn_b[a1e];
    float f0 = fc_b[a0],   f1 = fc_b[a1e];
    #pragma unroll 8
    for (int c = 0; c < 64; ++c) {
        float zc = z[c];
        l0 = fmaf(zc, awT[c * 500 + a0],  l0);
        l1 = fmaf(zc, awT[c * 500 + a1e], l1);
        f0 = fmaf(zc, fwT[c * 500 + a0],  f0);
        f1 = fmaf(zc, fwT[c * 500 + a1e], f1);
    }
    float v0 = 1.f / (1.f + expf(-l0));
    float v1 = (a1 < NOUT) ? 1.f / (1.f + expf(-l1)) : 0.f;
    if (a1 >= NOUT) f1 = -1e30f;
    att[a0] = v0; att[a1] = v1;
    msk[a0] = 0;  msk[a1] = 0;
    __syncthreads();

    // wave 0: top-20 over 500 sigmoids (ties -> lower index, matching lax.top_k)
    int selidx = 0;
    if (wv == 0) {
        float va[8];
        #pragma unroll
        for (int j = 0; j < 8; ++j) {
            int id = j * 64 + ln;
            va[j] = (id < NOUT) ? att[id] : 0.f;   // sigmoid > 0 for valid
        }
        for (int s = 0; s < NSEL; ++s) {
            float bv = va[0]; int bj = 0;
            #pragma unroll
            for (int j = 1; j < 8; ++j)
                if (va[j] > bv) { bv = va[j]; bj = j; }
            unsigned long long k =
                ((unsigned long long)__float_as_uint(bv) << 32)
                | (unsigned)(0xFFFFFFFFu - (unsigned)(bj * 64 + ln));
            for (int o = 32; o > 0; o >>= 1) {
                unsigned long long other = __shfl_xor(k, o);
                if (other > k) k = other;
            }
            int widx = (int)(0xFFFFFFFFu - (unsigned)(k & 0xFFFFFFFFu));
            if (ln == s) selidx = widx;
            if ((widx & 63) == ln) va[widx >> 6] = 0.f;
            if (ln == 0) msk[widx] = 1;
        }
    }
    __syncthreads();

    // softmax over all 500
    float mx = fmaxf(f0, f1);
    for (int o = 32; o > 0; o >>= 1) mx = fmaxf(mx, __shfl_xor(mx, o));
    if (ln == 0) rs[wv] = mx;
    __syncthreads();
    mx = fmaxf(fmaxf(rs[0], rs[1]), fmaxf(rs[2], rs[3]));
    __syncthreads();
    float e0 = expf(f0 - mx);
    float e1 = (a1 < NOUT) ? expf(f1 - mx) : 0.f;
    float sm = e0 + e1;
    for (int o = 32; o > 0; o >>= 1) sm += __shfl_xor(sm, o);
    if (ln == 0) rs[wv] = sm;
    __syncthreads();
    float Z = rs[0] + rs[1] + rs[2] + rs[3];

    float p0 = msk[a0] ? (e0 / Z) : 0.f;
    float p1 = (a1 < NOUT && msk[a1]) ? (e1 / Z) : 0.f;
    pa[a0] = p0; pa[a1] = p1;
    __syncthreads();

    // wave 0: renormalize + 17-iter water-filling on the 20 selected
    // (unselected weights are exactly 0.0 and are fixed points of the update)
    if (wv == 0) {
        float w = (ln < NSEL) ? pa[selidx] : 0.f;
        float S = w;
        for (int o = 32; o > 0; o >>= 1) S += __shfl_xor(S, o);
        w = w / (S + 1e-8f);
        for (int it = 0; it < 17; ++it) {
            float wc = fminf(fmaxf(w, 0.f), UBV);
            float lo = w - wc;
            float ns = (wc != UBV) ? wc : 0.f;
            for (int o = 32; o > 0; o >>= 1) {
                lo += __shfl_xor(lo, o);
                ns += __shfl_xor(ns, o);
            }
            if (ns == 0.f) ns = 1.f;
            w = (wc != UBV) ? wc + lo * wc / ns : wc;
        }
        if (ln < NSEL) out[(size_t)b * NOUT + selidx] = w;
    }
    if (!msk[a0]) out[(size_t)b * NOUT + a0] = 0.f;
    if (a1 < NOUT && !msk[a1]) out[(size_t)b * NOUT + a1] = 0.f;
}

extern "C" void kernel_launch(void* const* d_in, const int* in_sizes, int n_in,
                              void* d_out, int out_size, void* d_ws, size_t ws_size,
                              hipStream_t stream)
{
    const float* x   = (const float*)d_in[0];
    const float* c1w = (const float*)d_in[1];
    const float* c1b = (const float*)d_in[2];
    const float* c2w = (const float*)d_in[3];
    const float* c2b = (const float*)d_in[4];
    const float* pw  = (const float*)d_in[5];
    const float* pb  = (const float*)d_in[6];
    const float* aw  = (const float*)d_in[7];
    const float* ab  = (const float*)d_in[8];
    const float* fw  = (const float*)d_in[9];
    const float* fb  = (const float*)d_in[10];

    float* ws  = (float*)d_ws;
    float* out = (float*)d_out;

    (void)hipFuncSetAttribute((const void*)conv_kernel,
                              hipFuncAttributeMaxDynamicSharedMemorySize,
                              LDS_BYTES);

    prep_kernel<<<128, 256, 0, stream>>>(c1w, c2w, aw, fw, ws);
    conv_kernel<<<2048, 256, LDS_BYTES, stream>>>(x, ws, c1b, c2b, ws + OFF_POOLED);
    head_kernel<<<2048, 256, 0, stream>>>(ws, pw, pb, ab, fb, out);
}

// Round 10
// 478.579 us; speedup vs baseline: 1.1049x; 1.1049x over previous
//
#include <hip/hip_runtime.h>
#include <hip/hip_bf16.h>

#define T 252
#define NOUT 500
#define NSEL 20
#define UBV 0.1f

// LDS activation planes: [row = 16 zero-pad + 256 t][64 ch bf16 = 128 B], XOR-swizzled
// 16B chunks: chunk' = chunk ^ (row & 7). Row stride 32 dwords, 272 rows, 2 planes.
#define ROWS 272
#define PLANE_U (ROWS * 32)           // 8704 uints per plane
#define LDS_BYTES (2 * PLANE_U * 4)   // 69632 B

// ws layout (floats):
//   [0)        AF : W MFMA A-frags, 384 frags x 256 dwords    98304
//   [98304)    awT : attn_w^T [c][a]                          32000
//   [130304)   fwT : fc_w^T   [c][a]                          32000
//   [162304)   pooled [B][64]                                 131072
#define OFF_AWT    98304
#define OFF_FWT    130304
#define OFF_POOLED 162304

typedef short bf8 __attribute__((ext_vector_type(8)));   // 8 bf16 = 4 VGPR
typedef float f32x4 __attribute__((ext_vector_type(4)));

static __device__ __forceinline__ unsigned short f2bf(float f) {
    unsigned u = __float_as_uint(f);
    return (unsigned short)((u + 0x7fffu + ((u >> 16) & 1u)) >> 16);   // RNE
}
static __device__ __forceinline__ float bf2f(unsigned short h) {
    return __uint_as_float(((unsigned)h) << 16);
}
// pack two floats -> two bf16 (RNE); lowers to v_cvt_pk_bf16_f32 where available
static __device__ __forceinline__ unsigned pk2bf(float a, float b) {
    __hip_bfloat162 h = __float22bfloat162_rn(float2{a, b});
    unsigned u; __builtin_memcpy(&u, &h, 4); return u;
}
static __device__ __forceinline__ float bf_lo_f(unsigned u) { return __uint_as_float(u << 16); }
static __device__ __forceinline__ float bf_hi_f(unsigned u) { return __uint_as_float(u & 0xffff0000u); }
// uint index of 16B chunk base, swizzled
static __device__ __forceinline__ int swz(int row, int chunk) {
    return row * 32 + ((chunk ^ (row & 7)) << 2);
}

// ---------- prep: pack W into A-fragments + head transposes ----------
// fragid = ((((buf*4+lvl)*2+Kt)*3+tap)*4+m)*2+s ; per frag: [lane][4 dwords]
// A-frag lane map (16x16x32 bf16): c = m*16 + (lane&15), i = Kt*32 + (lane>>4)*8 + j
__global__ __launch_bounds__(256) void prep_kernel(
    const float* __restrict__ w1, const float* __restrict__ w2,
    const float* __restrict__ aw, const float* __restrict__ fw,
    float* __restrict__ ws)
{
    int gid = blockIdx.x * 256 + threadIdx.x;
    if (gid < 24576) {
        int frag = gid >> 6, lane = gid & 63;
        int s   = frag & 1;
        int m   = (frag >> 1) & 3;
        int t3  = frag >> 3;
        int tap = t3 % 3;
        int q   = t3 / 3;
        int Kt  = q & 1;
        int lvl = (q >> 1) & 3;
        int buf = q >> 3;
        int c  = m * 16 + (lane & 15);
        int i0 = Kt * 32 + (lane >> 4) * 8;
        const float* W = (buf ? w2 : w1) + lvl * 12288 + c * 192;
        unsigned short v[8];
        for (int j = 0; j < 8; ++j) {
            float x = W[(i0 + j) * 3 + tap];
            unsigned short hi = f2bf(x);
            if (s == 0) v[j] = hi;
            else        v[j] = f2bf(x - bf2f(hi));
        }
        unsigned* dst = (unsigned*)ws + frag * 256 + lane * 4;
        for (int d = 0; d < 4; ++d)
            dst[d] = (unsigned)v[2 * d] | ((unsigned)v[2 * d + 1] << 16);
    }
    if (gid < 32000) {
        int a = gid >> 6, c = gid & 63;   // src [a][c]
        ws[OFF_AWT + c * 500 + a] = aw[gid];
        ws[OFF_FWT + c * 500 + a] = fw[gid];
    }
}

extern __shared__ unsigned short lds[];

#define MFMA(A, B, C) __builtin_amdgcn_mfma_f32_16x16x32_bf16((A), (B), (C), 0, 0, 0)

// one 64ch x 64t conv GEMM for this wave: acc = bias + sum over (Kt,tap) of W*act
static __device__ __forceinline__ void conv_mm(
    const uint4* __restrict__ AF4,
    const unsigned* __restrict__ Lh, const unsigned* __restrict__ Ll,
    const float* __restrict__ bias,
    int cvlvl, int d, int Rb, int g, int g4, int lane,
    f32x4 acc[4][4])
{
    #pragma unroll
    for (int m = 0; m < 4; ++m) {
        float4 bv = *(const float4*)(bias + m * 16 + g4);
        #pragma unroll
        for (int nn = 0; nn < 4; ++nn)
            acc[m][nn] = (f32x4){bv.x, bv.y, bv.z, bv.w};
    }
    #pragma unroll
    for (int Kt = 0; Kt < 2; ++Kt) {
        #pragma unroll
        for (int tap = 0; tap < 3; ++tap) {
            const int fb = ((cvlvl * 2 + Kt) * 3 + tap) * 8;
            const uint4* af = AF4 + fb * 64 + lane;
            uint4 ta[4], tb[4];
            #pragma unroll
            for (int m = 0; m < 4; ++m) { ta[m] = af[m * 128]; tb[m] = af[m * 128 + 64]; }
            // swizzle is linear in nn: (row+16)&7 == row&7 -> base + nn*512
            const int shift = (2 - tap) * d;
            const int row0  = Rb - shift;
            const int ui0   = row0 * 32 + ((((Kt << 2) + g) ^ (row0 & 7)) << 2);
            bf8 Bh[4], Bl[4];
            #pragma unroll
            for (int nn = 0; nn < 4; ++nn) {
                Bh[nn] = *(const bf8*)(Lh + ui0 + nn * 512);
                Bl[nn] = *(const bf8*)(Ll + ui0 + nn * 512);
            }
            // T5: boost this wave while it drains the MFMA burst; co-resident
            // block's wave on this SIMD is at an unrelated phase (R8: conv −21 µs)
            __builtin_amdgcn_s_setprio(1);
            #pragma unroll
            for (int m = 0; m < 4; ++m) {
                bf8 Ah = *(bf8*)&ta[m];
                bf8 Al = *(bf8*)&tb[m];
                #pragma unroll
                for (int nn = 0; nn < 4; ++nn) {
                    f32x4 a = acc[m][nn];
                    a = MFMA(Ah, Bh[nn], a);
                    a = MFMA(Ah, Bl[nn], a);   // hi*lo
                    a = MFMA(Al, Bh[nn], a);   // lo*hi (lo*lo dropped: ~2^-18)
                    acc[m][nn] = a;
                }
            }
            __builtin_amdgcn_s_setprio(0);
        }
    }
}

// waves_per_eu(2,2): true occupancy is LDS-bound at 2 blocks/CU = 2 waves/SIMD.
// __launch_bounds__(256,2) made hipcc budget 4 waves/EU -> 128-VGPR cap, which
// caused spills in R3/R9 and pins R8 at 128 + 7.9MB scratch. This states the
// real target (2 waves/EU -> 256 VGPR budget) so the scheduler can hoist
// next-phase ds_reads/A-loads across MFMA bursts without spilling.
__global__ __launch_bounds__(256)
__attribute__((amdgpu_waves_per_eu(2, 2)))
void conv_kernel(
    const float* __restrict__ x,
    const float* __restrict__ ws,
    const float* __restrict__ b1,
    const float* __restrict__ b2,
    float* __restrict__ pooled)
{
    const int b    = blockIdx.x;
    const int tid  = threadIdx.x;        // 0..255
    const int lane = tid & 63;
    const int wv   = tid >> 6;           // 4 waves; wave handles ntiles 4wv..4wv+3

    unsigned* Lh = (unsigned*)lds;
    unsigned* Ll = Lh + PLANE_U;

    // zero pad rows 0..15 (t<0) and 268..271 (t>=252), both planes (whole rows)
    for (int j = tid; j < 640; j += 256) {
        int r20 = j >> 5, col = j & 31;
        int r = (r20 < 16) ? r20 : (252 + r20);
        Lh[r * 32 + col] = 0u;
        Ll[r * 32 + col] = 0u;
    }
    // ingest x[b]: [252][64] fp32 -> split hi/lo bf16 planes (swizzled)
    const float4* xb = (const float4*)(x + (size_t)b * (T * 64));
    for (int v = tid; v < T * 16; v += 256) {
        float4 xv = xb[v];
        int t = v >> 4, f4 = v & 15;              // channel base = 4*f4
        unsigned h01 = pk2bf(xv.x, xv.y);
        unsigned h23 = pk2bf(xv.z, xv.w);
        unsigned l01 = pk2bf(xv.x - bf_lo_f(h01), xv.y - bf_hi_f(h01));
        unsigned l23 = pk2bf(xv.z - bf_lo_f(h23), xv.w - bf_hi_f(h23));
        int row = 16 + t;
        int ui = swz(row, f4 >> 1) + ((f4 & 1) << 1);
        Lh[ui]     = h01;
        Lh[ui + 1] = h23;
        Ll[ui]     = l01;
        Ll[ui + 1] = l23;
    }

    const int g    = lane >> 4;               // 0..3
    const int g4   = g << 2;
    const int ln16 = lane & 15;
    const int Rb   = 16 + 64 * wv + ln16;     // D/B row base for this thread (nn=0)

    // residual h in fp32 registers, D-layout: hr[m][nn][j] = h[c = m*16+g4+j][t = 64wv+16nn+ln16]
    float hr[4][4][4];
    #pragma unroll
    for (int m = 0; m < 4; ++m)
        #pragma unroll
        for (int nn = 0; nn < 4; ++nn) {
            int t = 64 * wv + 16 * nn + ln16;
            if (t < T) {
                float4 v = xb[t * 16 + m * 4 + g];
                hr[m][nn][0] = v.x; hr[m][nn][1] = v.y;
                hr[m][nn][2] = v.z; hr[m][nn][3] = v.w;
            } else {
                hr[m][nn][0] = 0.f; hr[m][nn][1] = 0.f;
                hr[m][nn][2] = 0.f; hr[m][nn][3] = 0.f;
            }
        }
    __syncthreads();

    const uint4* AF4 = (const uint4*)ws;

    // epilogue write bases (linear in nn: +512)
    int ue[4];
    #pragma unroll
    for (int m = 0; m < 4; ++m)
        ue[m] = Rb * 32 + (((2 * m + (g >> 1)) ^ (Rb & 7)) << 2) + ((g & 1) << 1);

    for (int lvl = 0; lvl < 4; ++lvl) {
        const int d = 1 << lvl;
        f32x4 acc[4][4];

        // ---- conv1: reads h-plane ----
        conv_mm(AF4, Lh, Ll, b1 + lvl * 64, 0 * 4 + lvl, d, Rb, g, g4, lane, acc);
        __syncthreads();   // all h-plane reads done
        #pragma unroll
        for (int m = 0; m < 4; ++m)
            #pragma unroll
            for (int nn = 0; nn < 4; ++nn) {
                float o0 = fmaxf(acc[m][nn][0], 0.f);
                float o1 = fmaxf(acc[m][nn][1], 0.f);
                float o2 = fmaxf(acc[m][nn][2], 0.f);
                float o3 = fmaxf(acc[m][nn][3], 0.f);
                uint2 wh, wl;
                wh.x = pk2bf(o0, o1);
                wh.y = pk2bf(o2, o3);
                wl.x = pk2bf(o0 - bf_lo_f(wh.x), o1 - bf_hi_f(wh.x));
                wl.y = pk2bf(o2 - bf_lo_f(wh.y), o3 - bf_hi_f(wh.y));
                int ui = ue[m] + nn * 512;
                *(uint2*)(Lh + ui) = wh;
                *(uint2*)(Ll + ui) = wl;
            }
        __syncthreads();   // o1 visible

        // ---- conv2: reads o1-plane ----
        conv_mm(AF4, Lh, Ll, b2 + lvl * 64, 1 * 4 + lvl, d, Rb, g, g4, lane, acc);
        // residual + relu, fp32 in registers
        #pragma unroll
        for (int m = 0; m < 4; ++m)
            #pragma unroll
            for (int nn = 0; nn < 4; ++nn)
                #pragma unroll
                for (int j = 0; j < 4; ++j)
                    hr[m][nn][j] = fmaxf(fmaxf(acc[m][nn][j], 0.f) + hr[m][nn][j], 0.f);

        if (lvl < 3) {
            __syncthreads();   // all o1-plane reads done
            #pragma unroll
            for (int m = 0; m < 4; ++m)
                #pragma unroll
                for (int nn = 0; nn < 4; ++nn) {
                    float h0 = hr[m][nn][0], h1 = hr[m][nn][1];
                    float h2 = hr[m][nn][2], h3 = hr[m][nn][3];
                    uint2 wh, wl;
                    wh.x = pk2bf(h0, h1);
                    wh.y = pk2bf(h2, h3);
                    wl.x = pk2bf(h0 - bf_lo_f(wh.x), h1 - bf_hi_f(wh.x));
                    wl.y = pk2bf(h2 - bf_lo_f(wh.y), h3 - bf_hi_f(wh.y));
                    int ui = ue[m] + nn * 512;
                    *(uint2*)(Lh + ui) = wh;
                    *(uint2*)(Ll + ui) = wl;
                }
            __syncthreads();   // h_new visible
        }
    }

    // ---- max-pool over t, directly from hr registers ----
    __syncthreads();           // lvl3 conv2 o1-plane reads done everywhere; LDS free
    {
        const bool t3ok = (64 * wv + 48 + ln16) < T;   // mask t>=252 garbage (wv==3 only)
        float pm[4][4];
        #pragma unroll
        for (int m = 0; m < 4; ++m)
            #pragma unroll
            for (int j = 0; j < 4; ++j) {
                float p = fmaxf(fmaxf(hr[m][0][j], hr[m][1][j]), hr[m][2][j]);
                if (t3ok) p = fmaxf(p, hr[m][3][j]);
                pm[m][j] = p;
            }
        #pragma unroll
        for (int off = 1; off < 16; off <<= 1)
            #pragma unroll
            for (int m = 0; m < 4; ++m)
                #pragma unroll
                for (int j = 0; j < 4; ++j)
                    pm[m][j] = fmaxf(pm[m][j], __shfl_xor(pm[m][j], off));
        float* fp = (float*)lds;
        if (ln16 == 0) {
            #pragma unroll
            for (int m = 0; m < 4; ++m)
                #pragma unroll
                for (int j = 0; j < 4; ++j)
                    fp[wv * 64 + m * 16 + g4 + j] = pm[m][j];
        }
        __syncthreads();
        if (tid < 64) {
            float mm = fmaxf(fmaxf(fp[tid], fp[tid + 64]),
                             fmaxf(fp[tid + 128], fp[tid + 192]));
            pooled[(size_t)b * 64 + tid] = mm;
        }
    }
}

// ---------- head: GEMVs + wave-local top-20 + softmax + wave-local rebalance ----------
__global__ __launch_bounds__(256) void head_kernel(
    const float* __restrict__ ws,
    const float* __restrict__ proj_w,
    const float* __restrict__ proj_b,
    const float* __restrict__ attn_b,
    const float* __restrict__ fc_b,
    float* __restrict__ out)
{
    const float* awT    = ws + OFF_AWT;
    const float* fwT    = ws + OFF_FWT;
    const float* pooled = ws + OFF_POOLED;

    __shared__ float z[64];
    __shared__ float att[512];
    __shared__ float pa[512];
    __shared__ int   msk[512];
    __shared__ float rs[4];

    const int b   = blockIdx.x;
    const int tid = threadIdx.x;
    const int wv  = tid >> 6, ln = tid & 63;

    // z = relu(pooled @ proj_w^T + proj_b) — 4 threads per output, shfl-reduced
    {
        const int outc = tid >> 2, part = tid & 3;
        const float* pw = proj_w + outc * 64 + part * 16;
        const float* pl = pooled + (size_t)b * 64 + part * 16;
        float s = 0.f;
        #pragma unroll
        for (int c = 0; c < 16; ++c) s = fmaf(pw[c], pl[c], s);
        s += __shfl_xor(s, 1);
        s += __shfl_xor(s, 2);
        if (part == 0) z[outc] = fmaxf(s + proj_b[outc], 0.f);
    }
    __syncthreads();

    const int a0  = tid;
    const int a1  = tid + 256;
    const int a1e = (a1 < NOUT) ? a1 : (NOUT - 1);

    // attn = sigmoid(z @ attn_w^T + attn_b); fc logits too (independent of top-k)
    float l0 = attn_b[a0], l1 = attn_b[a1e];
    float f0 = fc_b[a0],   f1 = fc_b[a1e];
    #pragma unroll 8
    for (int c = 0; c < 64; ++c) {
        float zc = z[c];
        l0 = fmaf(zc, awT[c * 500 + a0],  l0);
        l1 = fmaf(zc, awT[c * 500 + a1e], l1);
        f0 = fmaf(zc, fwT[c * 500 + a0],  f0);
        f1 = fmaf(zc, fwT[c * 500 + a1e], f1);
    }
    float v0 = 1.f / (1.f + expf(-l0));
    float v1 = (a1 < NOUT) ? 1.f / (1.f + expf(-l1)) : 0.f;
    if (a1 >= NOUT) f1 = -1e30f;
    att[a0] = v0; att[a1] = v1;
    msk[a0] = 0;  msk[a1] = 0;
    __syncthreads();

    // wave 0: top-20 over 500 sigmoids (ties -> lower index, matching lax.top_k)
    int selidx = 0;
    if (wv == 0) {
        float va[8];
        #pragma unroll
        for (int j = 0; j < 8; ++j) {
            int id = j * 64 + ln;
            va[j] = (id < NOUT) ? att[id] : 0.f;   // sigmoid > 0 for valid
        }
        for (int s = 0; s < NSEL; ++s) {
            float bv = va[0]; int bj = 0;
            #pragma unroll
            for (int j = 1; j < 8; ++j)
                if (va[j] > bv) { bv = va[j]; bj = j; }
            unsigned long long k =
                ((unsigned long long)__float_as_uint(bv) << 32)
                | (unsigned)(0xFFFFFFFFu - (unsigned)(bj * 64 + ln));
            for (int o = 32; o > 0; o >>= 1) {
                unsigned long long other = __shfl_xor(k, o);
                if (other > k) k = other;
            }
            int widx = (int)(0xFFFFFFFFu - (unsigned)(k & 0xFFFFFFFFu));
            if (ln == s) selidx = widx;
            if ((widx & 63) == ln) va[widx >> 6] = 0.f;
            if (ln == 0) msk[widx] = 1;
        }
    }
    __syncthreads();

    // softmax over all 500
    float mx = fmaxf(f0, f1);
    for (int o = 32; o > 0; o >>= 1) mx = fmaxf(mx, __shfl_xor(mx, o));
    if (ln == 0) rs[wv] = mx;
    __syncthreads();
    mx = fmaxf(fmaxf(rs[0], rs[1]), fmaxf(rs[2], rs[3]));
    __syncthreads();
    float e0 = expf(f0 - mx);
    float e1 = (a1 < NOUT) ? expf(f1 - mx) : 0.f;
    float sm = e0 + e1;
    for (int o = 32; o > 0; o >>= 1) sm += __shfl_xor(sm, o);
    if (ln == 0) rs[wv] = sm;
    __syncthreads();
    float Z = rs[0] + rs[1] + rs[2] + rs[3];

    float p0 = msk[a0] ? (e0 / Z) : 0.f;
    float p1 = (a1 < NOUT && msk[a1]) ? (e1 / Z) : 0.f;
    pa[a0] = p0; pa[a1] = p1;
    __syncthreads();

    // wave 0: renormalize + 17-iter water-filling on the 20 selected
    // (unselected weights are exactly 0.0 and are fixed points of the update)
    if (wv == 0) {
        float w = (ln < NSEL) ? pa[selidx] : 0.f;
        float S = w;
        for (int o = 32; o > 0; o >>= 1) S += __shfl_xor(S, o);
        w = w / (S + 1e-8f);
        for (int it = 0; it < 17; ++it) {
            float wc = fminf(fmaxf(w, 0.f), UBV);
            float lo = w - wc;
            float ns = (wc != UBV) ? wc : 0.f;
            for (int o = 32; o > 0; o >>= 1) {
                lo += __shfl_xor(lo, o);
                ns += __shfl_xor(ns, o);
            }
            if (ns == 0.f) ns = 1.f;
            w = (wc != UBV) ? wc + lo * wc / ns : wc;
        }
        if (ln < NSEL) out[(size_t)b * NOUT + selidx] = w;
    }
    if (!msk[a0]) out[(size_t)b * NOUT + a0] = 0.f;
    if (a1 < NOUT && !msk[a1]) out[(size_t)b * NOUT + a1] = 0.f;
}

extern "C" void kernel_launch(void* const* d_in, const int* in_sizes, int n_in,
                              void* d_out, int out_size, void* d_ws, size_t ws_size,
                              hipStream_t stream)
{
    const float* x   = (const float*)d_in[0];
    const float* c1w = (const float*)d_in[1];
    const float* c1b = (const float*)d_in[2];
    const float* c2w = (const float*)d_in[3];
    const float* c2b = (const float*)d_in[4];
    const float* pw  = (const float*)d_in[5];
    const float* pb  = (const float*)d_in[6];
    const float* aw  = (const float*)d_in[7];
    const float* ab  = (const float*)d_in[8];
    const float* fw  = (const float*)d_in[9];
    const float* fb  = (const float*)d_in[10];

    float* ws  = (float*)d_ws;
    float* out = (float*)d_out;

    (void)hipFuncSetAttribute((const void*)conv_kernel,
                              hipFuncAttributeMaxDynamicSharedMemorySize,
                              LDS_BYTES);

    prep_kernel<<<128, 256, 0, stream>>>(c1w, c2w, aw, fw, ws);
    conv_kernel<<<2048, 256, LDS_BYTES, stream>>>(x, ws, c1b, c2b, ws + OFF_POOLED);
    head_kernel<<<2048, 256, 0, stream>>>(ws, pw, pb, ab, fb, out);
}